// Round 16
// baseline (246.146 us; speedup 1.0000x reference)
//
#include <hip/hip_runtime.h>
#include <hip/hip_cooperative_groups.h>
#include <math.h>

namespace cg = cooperative_groups;

// SMEFTNet forward. B=128, N=128, H=16.
// Primary: ONE cooperative launch (phases A/B/C with 2 grid.sync()s).
//   R15 failure diagnosed: no VGPR cap -> >128 VGPR -> only 3 blocks/CU ->
//   1024-block cooperative launch exceeds co-residency -> launch rejected.
//   Fix: __launch_bounds__(256,4) caps VGPR at 128 -> exactly 4 blocks/CU.
// Safety: check the launch result; on any failure fall back to the verified
//   R13 3-kernel pipeline (identical math, 30.2us). Deterministic both ways.

#define BB 128
#define NN 128
#define BN (BB * NN)

typedef float f32x2 __attribute__((ext_vector_type(2)));

__device__ __forceinline__ f32x2 pk2(float s) { f32x2 r; r[0] = s; r[1] = s; return r; }
__device__ __forceinline__ f32x2 pkfma(f32x2 a, f32x2 b, f32x2 c) {
    return __builtin_elementwise_fma(a, b, c);
}
__device__ __forceinline__ f32x2 pkmax(f32x2 a, f32x2 b) {
    return __builtin_elementwise_max(a, b);
}

template <int CTRL>
__device__ __forceinline__ float dpp_add(float x) {
    int tmp = __builtin_amdgcn_update_dpp(0, __float_as_int(x), CTRL, 0xF, 0xF, true);
    return x + __int_as_float(tmp);
}

// Sum within each 16-lane row; result valid in lane (l|15) of each row.
__device__ __forceinline__ float grp16_sum(float x) {
    x = dpp_add<0xB1>(x);   // quad_perm [1,0,3,2]  (xor 1)
    x = dpp_add<0x4E>(x);   // quad_perm [2,3,0,1]  (xor 2)
    x = dpp_add<0x114>(x);  // row_shr:4
    x = dpp_add<0x118>(x);  // row_shr:8
    return x;
}

__device__ __forceinline__ float bcast_grp(float x, int bidx) {
    return __int_as_float(__builtin_amdgcn_ds_bpermute(bidx, __float_as_int(x)));
}

// ===================== shared phase bodies (device inline) =====================

__device__ __forceinline__ void conv0_body(
    int ni, int base, int lane, int wid, int t, int g, int bidx, int blockid,
    const float* __restrict__ ang,
    const float* __restrict__ w0, const float* __restrict__ b0,
    const float* __restrict__ w1, const float* __restrict__ b1,
    const float* __restrict__ nw0, const float* __restrict__ nb0,
    float* __restrict__ ang1, float* __restrict__ u1, float* __restrict__ v1,
    float (*hls)[17])
{
    const float2 ai = ((const float2*)ang)[ni];
    const float r2i = fmaf(ai.x, ai.x, ai.y * ai.y);
    const float abszi = __builtin_amdgcn_sqrtf(r2i);
    const float invi  = __builtin_amdgcn_rsqf(r2i);

    f32x2 u0b2[8], q02[8], wc2[8], ws2[8];
    #pragma unroll
    for (int p = 0; p < 8; ++p) {
        f32x2 wa  = *(const f32x2*)(w0 + 2 * p);
        f32x2 wb  = *(const f32x2*)(w0 + 16 + 2 * p);
        f32x2 wcv = *(const f32x2*)(w0 + 32 + 2 * p);
        f32x2 bb  = *(const f32x2*)(b0 + 2 * p);
        u0b2[p] = pkfma(pk2(abszi), wa - wcv, bb);   // absz_i*(Wa-Wc)+b0
        q02[p]  = wb + wcv;                          // Wb+Wc
        wc2[p]  = *(const f32x2*)(w0 + 48 + 2 * p);
        ws2[p]  = *(const f32x2*)(w0 + 64 + 2 * p);
    }

    float w1row[16], w1g[16];
    #pragma unroll
    for (int k = 0; k < 16; ++k) {
        w1row[k] = w1[k * 17 + t];
        w1g[k]   = w1[k * 17 + 16];
    }
    const float b1t = b1[t], b1g = b1[16];

    const int o   = lane & 31;
    const int kk  = o & 15;
    const bool isU = (o < 16);
    float wk[16];
    {
        const int off = isU ? 0 : 256;
        #pragma unroll
        for (int c = 0; c < 16; ++c) {
            float a_ = nw0[off + c * 16 + kk];
            float c_ = nw0[512 + c * 16 + kk];
            wk[c] = isU ? (a_ - c_) : (a_ + c_);
        }
    }
    const float accb = isU ? nb0[kk] : 0.0f;

    f32x2 A2[8];
    #pragma unroll
    for (int p = 0; p < 8; ++p) A2[p] = pk2(0.0f);
    float degf = 0.0f;

    #pragma unroll 4
    for (int jj = 0; jj < 8; ++jj) {
        const float2 aj = ((const float2*)ang)[base + jj * 16 + t];
        const float r2j = fmaf(aj.x, aj.x, aj.y * aj.y);
        const float abszj = __builtin_amdgcn_sqrtf(r2j);
        const float ivj   = __builtin_amdgcn_rsqf(r2j);
        const float dre = ai.x - aj.x, dim = ai.y - aj.y;
        const float d2 = fmaf(dre, dre, dim * dim);
        const float adjf = (d2 <= 0.16f) ? 1.0f : 0.0f;
        degf += adjf;
        const float inv = fminf(invi * ivj, 1e12f);
        const f32x2 cos2 = pk2(fmaf(ai.x, aj.x, ai.y * aj.y) * inv);
        const f32x2 sin2 = pk2(fmaf(ai.y, aj.x, -(ai.x * aj.y)) * inv);
        const f32x2 ab2 = pk2(abszj);
        const f32x2 adj2 = pk2(adjf);
        #pragma unroll
        for (int p = 0; p < 8; ++p) {
            f32x2 z = pkfma(ab2, q02[p], u0b2[p]);
            z = pkfma(cos2, wc2[p], z);
            z = pkfma(sin2, ws2[p], z);
            f32x2 a = pkmax(z, z * 0.01f);
            A2[p] = pkfma(a, adj2, A2[p]);
        }
    }

    float Ak[16];
    #pragma unroll
    for (int p = 0; p < 8; ++p) {
        Ak[2 * p]     = bcast_grp(grp16_sum(A2[p][0]), bidx);
        Ak[2 * p + 1] = bcast_grp(grp16_sum(A2[p][1]), bidx);
    }
    const float invdeg = __builtin_amdgcn_rcpf(bcast_grp(grp16_sum(degf), bidx));

    float s = 0.0f, sg = 0.0f;
    #pragma unroll
    for (int k = 0; k < 16; ++k) {
        s  = fmaf(Ak[k], w1row[k], s);
        sg = fmaf(Ak[k], w1g[k], sg);
    }
    const float mt    = fmaf(s, invdeg, b1t);
    const float gamma = fmaf(sg, invdeg, b1g);

    {   // rotation (v_cos/v_sin take revolutions); norm preserved -> store invi
        const float gf = gamma - floorf(gamma);
        const float cs = __builtin_amdgcn_cosf(gf);
        const float sn = __builtin_amdgcn_sinf(gf);
        const float re2 = cs * ai.x - sn * ai.y;
        const float im2 = fmaf(sn, ai.x, cs * ai.y);
        if (t == 0) ((float4*)ang1)[ni] = make_float4(re2, im2, invi, 0.0f);
    }

    hls[wid * 4 + g][t] = mt;   // same-wave exchange (in-order, no barrier)

    #pragma unroll
    for (int p = 0; p < 2; ++p) {
        const int nl = (lane >> 5) + 2 * p;
        const int node = wid * 4 + nl;
        float acc = accb;
        #pragma unroll
        for (int c = 0; c < 16; ++c) acc = fmaf(hls[node][c], wk[c], acc);
        const int nout = blockid * 16 + node;
        if (isU) u1[nout * 16 + kk] = acc;
        else     v1[nout * 16 + kk] = acc;
    }
}

__device__ __forceinline__ void conv1_body(
    int ni, int base, int lane, int wid, int t, int bidx, int blockid,
    const float* __restrict__ pt, const float* __restrict__ ang1,
    const float* __restrict__ u1, const float* __restrict__ v1,
    const float* __restrict__ w0c, const float* __restrict__ w1c,
    const float* __restrict__ b1c, float* __restrict__ part)
{
    const float4 a4 = ((const float4*)ang1)[ni];
    const float rei = a4.x, imi = a4.y, invi = a4.z;
    const float ptf = pt[ni];

    f32x2 u0b2[8], wc2[8], ws2[8];
    {
        const float4* ug = (const float4*)(u1 + (size_t)ni * 16);
        float4 q0 = ug[0], q1 = ug[1], q2 = ug[2], q3 = ug[3];
        u0b2[0][0] = q0.x; u0b2[0][1] = q0.y; u0b2[1][0] = q0.z; u0b2[1][1] = q0.w;
        u0b2[2][0] = q1.x; u0b2[2][1] = q1.y; u0b2[3][0] = q1.z; u0b2[3][1] = q1.w;
        u0b2[4][0] = q2.x; u0b2[4][1] = q2.y; u0b2[5][0] = q2.z; u0b2[5][1] = q2.w;
        u0b2[6][0] = q3.x; u0b2[6][1] = q3.y; u0b2[7][0] = q3.z; u0b2[7][1] = q3.w;
    }
    #pragma unroll
    for (int p = 0; p < 8; ++p) {
        wc2[p] = *(const f32x2*)(w0c + 768 + 2 * p);
        ws2[p] = *(const f32x2*)(w0c + 784 + 2 * p);
    }

    float w1row[16], w1g[16];
    #pragma unroll
    for (int k = 0; k < 16; ++k) {
        w1row[k] = w1c[k * 17 + t];
        w1g[k]   = w1c[k * 17 + 16];
    }
    const float b1t = b1c[t], b1g = b1c[16];

    f32x2 A2[8];
    #pragma unroll
    for (int p = 0; p < 8; ++p) A2[p] = pk2(0.0f);
    float degf = 0.0f;

    #pragma unroll 4
    for (int jj = 0; jj < 8; ++jj) {
        const int j = base + jj * 16 + t;
        const float4 aj = ((const float4*)ang1)[j];
        f32x2 vj2[8];
        {
            const float4* vg = (const float4*)(v1 + (size_t)j * 16);
            float4 q0 = vg[0], q1 = vg[1], q2 = vg[2], q3 = vg[3];
            vj2[0][0] = q0.x; vj2[0][1] = q0.y; vj2[1][0] = q0.z; vj2[1][1] = q0.w;
            vj2[2][0] = q1.x; vj2[2][1] = q1.y; vj2[3][0] = q1.z; vj2[3][1] = q1.w;
            vj2[4][0] = q2.x; vj2[4][1] = q2.y; vj2[5][0] = q2.z; vj2[5][1] = q2.w;
            vj2[6][0] = q3.x; vj2[6][1] = q3.y; vj2[7][0] = q3.z; vj2[7][1] = q3.w;
        }
        const float dre = rei - aj.x, dim = imi - aj.y;
        const float d2 = fmaf(dre, dre, dim * dim);
        const float adjf = (d2 <= 0.16f) ? 1.0f : 0.0f;
        degf += adjf;
        const float inv = fminf(invi * aj.z, 1e12f);
        const f32x2 cos2 = pk2(fmaf(rei, aj.x, imi * aj.y) * inv);
        const f32x2 sin2 = pk2(fmaf(imi, aj.x, -(rei * aj.y)) * inv);
        const f32x2 adj2 = pk2(adjf);
        #pragma unroll
        for (int p = 0; p < 8; ++p) {
            f32x2 z = u0b2[p] + vj2[p];
            z = pkfma(cos2, wc2[p], z);
            z = pkfma(sin2, ws2[p], z);
            f32x2 a = pkmax(z, z * 0.01f);
            A2[p] = pkfma(a, adj2, A2[p]);
        }
    }

    float Ak[16];
    #pragma unroll
    for (int p = 0; p < 8; ++p) {
        Ak[2 * p]     = bcast_grp(grp16_sum(A2[p][0]), bidx);
        Ak[2 * p + 1] = bcast_grp(grp16_sum(A2[p][1]), bidx);
    }
    const float invdeg = __builtin_amdgcn_rcpf(bcast_grp(grp16_sum(degf), bidx));

    float s = 0.0f, sg = 0.0f;
    #pragma unroll
    for (int k = 0; k < 16; ++k) {
        s  = fmaf(Ak[k], w1row[k], s);
        sg = fmaf(Ak[k], w1g[k], sg);
    }
    const float mt    = fmaf(s, invdeg, b1t);
    const float gamma = fmaf(sg, invdeg, b1g);

    const float gf = gamma - floorf(gamma);
    const float cs = __builtin_amdgcn_cosf(gf);
    const float sn = __builtin_amdgcn_sinf(gf);
    const float re2 = cs * rei - sn * imi;
    const float im2 = fmaf(sn, rei, cs * imi);

    float pm  = ptf * mt;
    float pre = ptf * re2;
    float pim = ptf * im2;
    float ppt = ptf;
    pm  += __int_as_float(__builtin_amdgcn_ds_swizzle(__float_as_int(pm),  0x401F));
    pre += __int_as_float(__builtin_amdgcn_ds_swizzle(__float_as_int(pre), 0x401F));
    pim += __int_as_float(__builtin_amdgcn_ds_swizzle(__float_as_int(pim), 0x401F));
    ppt += __int_as_float(__builtin_amdgcn_ds_swizzle(__float_as_int(ppt), 0x401F));
    pm  += __shfl_xor(pm, 32);
    pre += __shfl_xor(pre, 32);
    pim += __shfl_xor(pim, 32);
    ppt += __shfl_xor(ppt, 32);

    float* po = part + (size_t)(blockid * 4 + wid) * 20;
    if (lane < 16)       po[lane] = pm;
    else if (lane == 16) po[16] = pre;
    else if (lane == 17) po[17] = pim;
    else if (lane == 18) po[18] = ppt;
}

__device__ __forceinline__ void readout_body(
    int b, int tt,
    const float* __restrict__ part,
    const float* __restrict__ w0, const float* __restrict__ b0,
    const float* __restrict__ w1, const float* __restrict__ b1,
    const float* __restrict__ w2, const float* __restrict__ b2,
    float* __restrict__ out,
    float* sbuf, float* xg, float* h1r)
{
    if (tt < 19) {
        float s0 = 0.0f, s1 = 0.0f, s2 = 0.0f, s3 = 0.0f;
        const float* pb = part + (size_t)b * 32 * 20 + tt;
        #pragma unroll
        for (int r = 0; r < 32; r += 4) {
            s0 += pb[(r + 0) * 20];
            s1 += pb[(r + 1) * 20];
            s2 += pb[(r + 2) * 20];
            s3 += pb[(r + 3) * 20];
        }
        sbuf[tt] = (s0 + s1) + (s2 + s3);
    }
    // one wave: LDS ops in-order, no barrier needed
    const float invd = __builtin_amdgcn_rcpf(sbuf[18]);
    if (tt < 18) xg[tt] = sbuf[tt] * invd;

    if (tt < 32) {
        float h = b0[tt];
        #pragma unroll
        for (int k = 0; k < 16; ++k) h = fmaf(xg[k], w0[k * 32 + tt], h);
        h = fmaxf(h, 0.01f * h);
        h1r[tt] = h;
    }
    if (tt < 32) {
        float h = b1[tt];
        #pragma unroll
        for (int k = 0; k < 32; ++k) h = fmaf(h1r[k], w1[k * 32 + tt], h);
        h = fmaxf(h, 0.01f * h);
        float p = h * w2[tt];
        #pragma unroll
        for (int off = 16; off; off >>= 1) p += __shfl_xor(p, off);
        if (tt == 0) {
            out[b * 3 + 0] = 1.0f / (1.0f + expf(-(p + b2[0])));
            out[b * 3 + 1] = xg[16];
            out[b * 3 + 2] = xg[17];
        }
    }
}

// ===================== primary: one cooperative launch =====================

__global__ __launch_bounds__(256, 4) void mono_kernel(
    const float* __restrict__ pt, const float* __restrict__ ang,
    const float* __restrict__ w0, const float* __restrict__ b0,
    const float* __restrict__ w1, const float* __restrict__ b1,
    const float* __restrict__ nw0, const float* __restrict__ nb0,
    const float* __restrict__ nw1, const float* __restrict__ nb1,
    const float* __restrict__ rw0, const float* __restrict__ rb0,
    const float* __restrict__ rw1, const float* __restrict__ rb1,
    const float* __restrict__ rw2, const float* __restrict__ rb2,
    float* __restrict__ ang1, float* __restrict__ u1, float* __restrict__ v1,
    float* __restrict__ part, float* __restrict__ out)
{
    const int tid  = threadIdx.x;
    const int lane = tid & 63;
    const int wid  = tid >> 6;
    const int t    = lane & 15;
    const int g    = lane >> 4;
    const int ni   = blockIdx.x * 16 + wid * 4 + g;
    const int base = (blockIdx.x >> 3) << 7;
    const int bidx = (lane | 15) << 2;

    __shared__ float hls[16][17];
    __shared__ float sbuf[19];
    __shared__ float xg[18];
    __shared__ float h1r[32];

    conv0_body(ni, base, lane, wid, t, g, bidx, blockIdx.x,
               ang, w0, b0, w1, b1, nw0, nb0, ang1, u1, v1, hls);

    cg::this_grid().sync();

    conv1_body(ni, base, lane, wid, t, bidx, blockIdx.x,
               pt, ang1, u1, v1, nw0, nw1, nb1, part);

    cg::this_grid().sync();

    if (blockIdx.x < BB && wid == 0) {
        readout_body(blockIdx.x, lane, part, rw0, rb0, rw1, rb1, rw2, rb2,
                     out, sbuf, xg, h1r);
    }
}

// ===================== fallback: verified R13 3-kernel path =====================

__global__ __launch_bounds__(256) void conv0_kernel(
    const float* __restrict__ ang,
    const float* __restrict__ w0, const float* __restrict__ b0,
    const float* __restrict__ w1, const float* __restrict__ b1,
    const float* __restrict__ nw0, const float* __restrict__ nb0,
    float* __restrict__ ang1, float* __restrict__ u1, float* __restrict__ v1)
{
    const int tid  = threadIdx.x;
    const int lane = tid & 63;
    const int wid  = tid >> 6;
    const int t    = lane & 15;
    const int g    = lane >> 4;
    const int ni   = blockIdx.x * 16 + wid * 4 + g;
    const int base = (blockIdx.x >> 3) << 7;
    const int bidx = (lane | 15) << 2;
    __shared__ float hls[16][17];
    conv0_body(ni, base, lane, wid, t, g, bidx, blockIdx.x,
               ang, w0, b0, w1, b1, nw0, nb0, ang1, u1, v1, hls);
}

__global__ __launch_bounds__(256) void conv1_kernel(
    const float* __restrict__ pt, const float* __restrict__ ang1,
    const float* __restrict__ u1, const float* __restrict__ v1,
    const float* __restrict__ w0c, const float* __restrict__ w1c,
    const float* __restrict__ b1c, float* __restrict__ part)
{
    const int tid  = threadIdx.x;
    const int lane = tid & 63;
    const int wid  = tid >> 6;
    const int t    = lane & 15;
    const int g    = lane >> 4;
    const int ni   = blockIdx.x * 16 + wid * 4 + g;
    const int base = (blockIdx.x >> 3) << 7;
    const int bidx = (lane | 15) << 2;
    (void)g;
    conv1_body(ni, base, lane, wid, t, bidx, blockIdx.x,
               pt, ang1, u1, v1, w0c, w1c, b1c, part);
}

__global__ __launch_bounds__(64) void readout_kernel(
    const float* __restrict__ part,
    const float* __restrict__ w0, const float* __restrict__ b0,
    const float* __restrict__ w1, const float* __restrict__ b1,
    const float* __restrict__ w2, const float* __restrict__ b2,
    float* __restrict__ out)
{
    __shared__ float sbuf[19];
    __shared__ float xg[18];
    __shared__ float h1r[32];
    readout_body(blockIdx.x, threadIdx.x, part, w0, b0, w1, b1, w2, b2,
                 out, sbuf, xg, h1r);
}

extern "C" void kernel_launch(void* const* d_in, const int* in_sizes, int n_in,
                              void* d_out, int out_size, void* d_ws, size_t ws_size,
                              hipStream_t stream) {
    const float* pt    = (const float*)d_in[0];
    const float* ang   = (const float*)d_in[1];
    const float* c0_w0 = (const float*)d_in[2];
    const float* c0_b0 = (const float*)d_in[3];
    const float* c0_w1 = (const float*)d_in[4];
    const float* c0_b1 = (const float*)d_in[5];
    const float* c1_w0 = (const float*)d_in[6];
    const float* c1_b0 = (const float*)d_in[7];
    const float* c1_w1 = (const float*)d_in[8];
    const float* c1_b1 = (const float*)d_in[9];
    const float* r_w0  = (const float*)d_in[10];
    const float* r_b0  = (const float*)d_in[11];
    const float* r_w1  = (const float*)d_in[12];
    const float* r_b1  = (const float*)d_in[13];
    const float* r_w2  = (const float*)d_in[14];
    const float* r_b2  = (const float*)d_in[15];
    float* out = (float*)d_out;
    float* ws = (float*)d_ws;

    float* ang1  = ws;                         // BN*4
    float* u1    = ang1 + (size_t)BN * 4;      // BN*16
    float* v1    = u1 + (size_t)BN * 16;       // BN*16
    float* partb = v1 + (size_t)BN * 16;       // 4096*20

    void* args[] = {
        (void*)&pt, (void*)&ang,
        (void*)&c0_w0, (void*)&c0_b0, (void*)&c0_w1, (void*)&c0_b1,
        (void*)&c1_w0, (void*)&c1_b0, (void*)&c1_w1, (void*)&c1_b1,
        (void*)&r_w0, (void*)&r_b0, (void*)&r_w1, (void*)&r_b1,
        (void*)&r_w2, (void*)&r_b2,
        (void*)&ang1, (void*)&u1, (void*)&v1, (void*)&partb, (void*)&out
    };
    hipError_t err = hipLaunchCooperativeKernel(
        (void*)mono_kernel, dim3(BN / 16), dim3(256), args, 0, stream);

    if (err != hipSuccess) {
        // fallback: verified 3-kernel pipeline (identical math)
        hipLaunchKernelGGL(conv0_kernel, dim3(BN / 16), dim3(256), 0, stream,
                           ang, c0_w0, c0_b0, c0_w1, c0_b1, c1_w0, c1_b0,
                           ang1, u1, v1);
        hipLaunchKernelGGL(conv1_kernel, dim3(BN / 16), dim3(256), 0, stream,
                           pt, ang1, u1, v1, c1_w0, c1_w1, c1_b1, partb);
        hipLaunchKernelGGL(readout_kernel, dim3(BB), dim3(64), 0, stream,
                           partb, r_w0, r_b0, r_w1, r_b1, r_w2, r_b2, out);
    }
}

// Round 17
// 30.099 us; speedup vs baseline: 8.1780x; 8.1780x over previous
//
#include <hip/hip_runtime.h>
#include <math.h>

// SMEFTNet forward. B=128, N=128, H=16.  FINAL: verified best (R6/R13,
// 30.2us, absmax 0.0). 3 launches: conv0+proj -> conv1+partials -> readout.
// 4 nodes/wave, lane = g*16+t; DPP-16 reduce + bpermute broadcast; packed
// f32x2 math; algebraic eliminations (w=adj/deg, sw==1, rank-1 conv0 h,
// fused conv1 projections, rotation in revolutions with norm carried).
// Fusion alternatives all measured worse: threadfence+atomic (R7: 166us),
// mega-block LDS (R10-12: VGPR clamp -> spills), cooperative grid.sync
// (R16: ~90us/sync). Launch overhead is structural; compute is converged.

#define BB 128
#define NN 128
#define BN (BB * NN)

typedef float f32x2 __attribute__((ext_vector_type(2)));

__device__ __forceinline__ f32x2 pk2(float s) { f32x2 r; r[0] = s; r[1] = s; return r; }
__device__ __forceinline__ f32x2 pkfma(f32x2 a, f32x2 b, f32x2 c) {
    return __builtin_elementwise_fma(a, b, c);
}
__device__ __forceinline__ f32x2 pkmax(f32x2 a, f32x2 b) {
    return __builtin_elementwise_max(a, b);
}

template <int CTRL>
__device__ __forceinline__ float dpp_add(float x) {
    int tmp = __builtin_amdgcn_update_dpp(0, __float_as_int(x), CTRL, 0xF, 0xF, true);
    return x + __int_as_float(tmp);
}

// Sum within each 16-lane row; result valid in lane (l|15) of each row.
__device__ __forceinline__ float grp16_sum(float x) {
    x = dpp_add<0xB1>(x);   // quad_perm [1,0,3,2]  (xor 1)
    x = dpp_add<0x4E>(x);   // quad_perm [2,3,0,1]  (xor 2)
    x = dpp_add<0x114>(x);  // row_shr:4
    x = dpp_add<0x118>(x);  // row_shr:8
    return x;
}

__device__ __forceinline__ float bcast_grp(float x, int bidx) {
    return __int_as_float(__builtin_amdgcn_ds_bpermute(bidx, __float_as_int(x)));
}

// ---------------- K1: conv0 + fused proj for conv1 ----------------
__global__ __launch_bounds__(256) void conv0_kernel(
    const float* __restrict__ ang,   // (B,N,2)
    const float* __restrict__ w0,    // c0_w0 (5,16)
    const float* __restrict__ b0,    // (16)
    const float* __restrict__ w1,    // c0_w1 (16,17)
    const float* __restrict__ b1,    // (17)
    const float* __restrict__ nw0,   // c1_w0 (50,16)
    const float* __restrict__ nb0,   // c1_b0 (16)
    float* __restrict__ ang1,        // (BN,4): re,im,inv,0
    float* __restrict__ u1,          // (BN,16)
    float* __restrict__ v1)          // (BN,16)
{
    const int tid  = threadIdx.x;
    const int lane = tid & 63;
    const int wid  = tid >> 6;
    const int t    = lane & 15;      // channel / j-sub-index
    const int g    = lane >> 4;      // node subgroup 0..3
    const int ni   = blockIdx.x * 16 + wid * 4 + g;
    const int base = (blockIdx.x >> 3) << 7;   // batch start node

    __shared__ float hls[16][17];

    // my node
    const float2 ai = ((const float2*)ang)[ni];
    const float r2i = fmaf(ai.x, ai.x, ai.y * ai.y);
    const float abszi = __builtin_amdgcn_sqrtf(r2i);
    const float invi  = __builtin_amdgcn_rsqf(r2i);

    // layer-0 row constants (wave-uniform -> s_load) + per-lane u0b
    f32x2 u0b2[8], q02[8], wc2[8], ws2[8];
    #pragma unroll
    for (int p = 0; p < 8; ++p) {
        f32x2 wa  = *(const f32x2*)(w0 + 2 * p);
        f32x2 wb  = *(const f32x2*)(w0 + 16 + 2 * p);
        f32x2 wcv = *(const f32x2*)(w0 + 32 + 2 * p);
        f32x2 bb  = *(const f32x2*)(b0 + 2 * p);
        u0b2[p] = pkfma(pk2(abszi), wa - wcv, bb);   // absz_i*(Wa-Wc)+b0
        q02[p]  = wb + wcv;                          // Wb+Wc
        wc2[p]  = *(const f32x2*)(w0 + 48 + 2 * p);
        ws2[p]  = *(const f32x2*)(w0 + 64 + 2 * p);
    }

    // prefetch w1 column t (per-lane) and gamma column (uniform)
    float w1row[16], w1g[16];
    #pragma unroll
    for (int k = 0; k < 16; ++k) {
        w1row[k] = w1[k * 17 + t];
        w1g[k]   = w1[k * 17 + 16];
    }
    const float b1t = b1[t], b1g = b1[16];

    // prefetch + combine proj weights: output o = lane&31 (k = o&15, u/v half)
    const int o   = lane & 31;
    const int kk  = o & 15;
    const bool isU = (o < 16);
    float wk[16];
    {
        const int off = isU ? 0 : 256;
        #pragma unroll
        for (int c = 0; c < 16; ++c) {
            float a_ = nw0[off + c * 16 + kk];
            float c_ = nw0[512 + c * 16 + kk];
            wk[c] = isU ? (a_ - c_) : (a_ + c_);
        }
    }
    const float accb = isU ? nb0[kk] : 0.0f;

    // j-loop: 8 iters, j = 16*jj + t
    f32x2 A2[8];
    #pragma unroll
    for (int p = 0; p < 8; ++p) A2[p] = pk2(0.0f);
    float degf = 0.0f;

    #pragma unroll 4
    for (int jj = 0; jj < 8; ++jj) {
        const float2 aj = ((const float2*)ang)[base + jj * 16 + t];
        const float r2j = fmaf(aj.x, aj.x, aj.y * aj.y);
        const float abszj = __builtin_amdgcn_sqrtf(r2j);
        const float ivj   = __builtin_amdgcn_rsqf(r2j);
        const float dre = ai.x - aj.x, dim = ai.y - aj.y;
        const float d2 = fmaf(dre, dre, dim * dim);
        const float adjf = (d2 <= 0.16f) ? 1.0f : 0.0f;
        degf += adjf;
        const float inv = fminf(invi * ivj, 1e12f);
        const f32x2 cos2 = pk2(fmaf(ai.x, aj.x, ai.y * aj.y) * inv);
        const f32x2 sin2 = pk2(fmaf(ai.y, aj.x, -(ai.x * aj.y)) * inv);
        const f32x2 ab2 = pk2(abszj);
        const f32x2 adj2 = pk2(adjf);
        #pragma unroll
        for (int p = 0; p < 8; ++p) {
            f32x2 z = pkfma(ab2, q02[p], u0b2[p]);
            z = pkfma(cos2, wc2[p], z);
            z = pkfma(sin2, ws2[p], z);
            f32x2 a = pkmax(z, z * 0.01f);
            A2[p] = pkfma(a, adj2, A2[p]);
        }
    }

    // reduce: 17 chains, 4-step DPP + bpermute broadcast from lane (l|15)
    const int bidx = (lane | 15) << 2;
    float Ak[16];
    #pragma unroll
    for (int p = 0; p < 8; ++p) {
        Ak[2 * p]     = bcast_grp(grp16_sum(A2[p][0]), bidx);
        Ak[2 * p + 1] = bcast_grp(grp16_sum(A2[p][1]), bidx);
    }
    const float degA = bcast_grp(grp16_sum(degf), bidx);
    const float invdeg = __builtin_amdgcn_rcpf(degA);

    // 2nd MLP layer: channel t (per-lane weights) + gamma (SGPR weights)
    float s = 0.0f, sg = 0.0f;
    #pragma unroll
    for (int k = 0; k < 16; ++k) {
        s  = fmaf(Ak[k], w1row[k], s);
        sg = fmaf(Ak[k], w1g[k], sg);
    }
    const float mt    = fmaf(s, invdeg, b1t);
    const float gamma = fmaf(sg, invdeg, b1g);

    // rotation (v_cos/v_sin take revolutions); norm preserved -> store invi
    {
        const float gf = gamma - floorf(gamma);
        const float cs = __builtin_amdgcn_cosf(gf);
        const float sn = __builtin_amdgcn_sinf(gf);
        const float re2 = cs * ai.x - sn * ai.y;
        const float im2 = fmaf(sn, ai.x, cs * ai.y);
        if (t == 0) ((float4*)ang1)[ni] = make_float4(re2, im2, invi, 0.0f);
    }

    // h-exchange (same-wave LDS, no barrier needed)
    hls[wid * 4 + g][t] = mt;

    // proj: 2 passes x 64 lanes = 128 outputs (4 nodes x (16 u + 16 v))
    #pragma unroll
    for (int p = 0; p < 2; ++p) {
        const int nl = (lane >> 5) + 2 * p;       // node local 0..3
        const int node = wid * 4 + nl;
        float acc = accb;
        #pragma unroll
        for (int c = 0; c < 16; ++c) acc = fmaf(hls[node][c], wk[c], acc);
        const int nout = (blockIdx.x * 16 + node);
        if (isU) u1[nout * 16 + kk] = acc;
        else     v1[nout * 16 + kk] = acc;
    }
}

// ---------------- K2: conv1 + per-wave readout partials ----------------
__global__ __launch_bounds__(256) void conv1_kernel(
    const float* __restrict__ pt,    // (B,N)
    const float* __restrict__ ang1,  // (BN,4): re,im,inv,0
    const float* __restrict__ u1,    // (BN,16)
    const float* __restrict__ v1,    // (BN,16)
    const float* __restrict__ w0,    // c1_w0 (50,16)
    const float* __restrict__ w1,    // c1_w1 (16,17)
    const float* __restrict__ b1,    // (17)
    float* __restrict__ part)        // (4096,20): [0..15]=sum pt*m, 16=re,17=im,18=sum pt
{
    const int tid  = threadIdx.x;
    const int lane = tid & 63;
    const int wid  = tid >> 6;
    const int t    = lane & 15;
    const int g    = lane >> 4;
    const int ni   = blockIdx.x * 16 + wid * 4 + g;
    const int base = (blockIdx.x >> 3) << 7;

    // my node
    const float4 a4 = ((const float4*)ang1)[ni];
    const float rei = a4.x, imi = a4.y, invi = a4.z;
    const float ptf = pt[ni];

    f32x2 u0b2[8], wc2[8], ws2[8];
    {
        const float4* ug = (const float4*)(u1 + (size_t)ni * 16);
        float4 q0 = ug[0], q1 = ug[1], q2 = ug[2], q3 = ug[3];
        u0b2[0][0] = q0.x; u0b2[0][1] = q0.y; u0b2[1][0] = q0.z; u0b2[1][1] = q0.w;
        u0b2[2][0] = q1.x; u0b2[2][1] = q1.y; u0b2[3][0] = q1.z; u0b2[3][1] = q1.w;
        u0b2[4][0] = q2.x; u0b2[4][1] = q2.y; u0b2[5][0] = q2.z; u0b2[5][1] = q2.w;
        u0b2[6][0] = q3.x; u0b2[6][1] = q3.y; u0b2[7][0] = q3.z; u0b2[7][1] = q3.w;
    }
    #pragma unroll
    for (int p = 0; p < 8; ++p) {
        wc2[p] = *(const f32x2*)(w0 + 768 + 2 * p);
        ws2[p] = *(const f32x2*)(w0 + 784 + 2 * p);
    }

    float w1row[16], w1g[16];
    #pragma unroll
    for (int k = 0; k < 16; ++k) {
        w1row[k] = w1[k * 17 + t];
        w1g[k]   = w1[k * 17 + 16];
    }
    const float b1t = b1[t], b1g = b1[16];

    f32x2 A2[8];
    #pragma unroll
    for (int p = 0; p < 8; ++p) A2[p] = pk2(0.0f);
    float degf = 0.0f;

    #pragma unroll 4
    for (int jj = 0; jj < 8; ++jj) {
        const int j = base + jj * 16 + t;
        const float4 aj = ((const float4*)ang1)[j];
        f32x2 vj2[8];
        {
            const float4* vg = (const float4*)(v1 + (size_t)j * 16);
            float4 q0 = vg[0], q1 = vg[1], q2 = vg[2], q3 = vg[3];
            vj2[0][0] = q0.x; vj2[0][1] = q0.y; vj2[1][0] = q0.z; vj2[1][1] = q0.w;
            vj2[2][0] = q1.x; vj2[2][1] = q1.y; vj2[3][0] = q1.z; vj2[3][1] = q1.w;
            vj2[4][0] = q2.x; vj2[4][1] = q2.y; vj2[5][0] = q2.z; vj2[5][1] = q2.w;
            vj2[6][0] = q3.x; vj2[6][1] = q3.y; vj2[7][0] = q3.z; vj2[7][1] = q3.w;
        }
        const float dre = rei - aj.x, dim = imi - aj.y;
        const float d2 = fmaf(dre, dre, dim * dim);
        const float adjf = (d2 <= 0.16f) ? 1.0f : 0.0f;
        degf += adjf;
        const float inv = fminf(invi * aj.z, 1e12f);
        const f32x2 cos2 = pk2(fmaf(rei, aj.x, imi * aj.y) * inv);
        const f32x2 sin2 = pk2(fmaf(imi, aj.x, -(rei * aj.y)) * inv);
        const f32x2 adj2 = pk2(adjf);
        #pragma unroll
        for (int p = 0; p < 8; ++p) {
            f32x2 z = u0b2[p] + vj2[p];
            z = pkfma(cos2, wc2[p], z);
            z = pkfma(sin2, ws2[p], z);
            f32x2 a = pkmax(z, z * 0.01f);
            A2[p] = pkfma(a, adj2, A2[p]);
        }
    }

    const int bidx = (lane | 15) << 2;
    float Ak[16];
    #pragma unroll
    for (int p = 0; p < 8; ++p) {
        Ak[2 * p]     = bcast_grp(grp16_sum(A2[p][0]), bidx);
        Ak[2 * p + 1] = bcast_grp(grp16_sum(A2[p][1]), bidx);
    }
    const float degA = bcast_grp(grp16_sum(degf), bidx);
    const float invdeg = __builtin_amdgcn_rcpf(degA);

    float s = 0.0f, sg = 0.0f;
    #pragma unroll
    for (int k = 0; k < 16; ++k) {
        s  = fmaf(Ak[k], w1row[k], s);
        sg = fmaf(Ak[k], w1g[k], sg);
    }
    const float mt    = fmaf(s, invdeg, b1t);
    const float gamma = fmaf(sg, invdeg, b1g);

    const float gf = gamma - floorf(gamma);
    const float cs = __builtin_amdgcn_cosf(gf);
    const float sn = __builtin_amdgcn_sinf(gf);
    const float re2 = cs * rei - sn * imi;
    const float im2 = fmaf(sn, rei, cs * imi);

    // per-wave readout partials: sum over the wave's 4 nodes.
    float pm  = ptf * mt;     // per-channel t
    float pre = ptf * re2;    // uniform within group
    float pim = ptf * im2;
    float ppt = ptf;
    // cross-group sum: xor16 (ds_swizzle) + xor32 (shfl)
    pm  += __int_as_float(__builtin_amdgcn_ds_swizzle(__float_as_int(pm),  0x401F));
    pre += __int_as_float(__builtin_amdgcn_ds_swizzle(__float_as_int(pre), 0x401F));
    pim += __int_as_float(__builtin_amdgcn_ds_swizzle(__float_as_int(pim), 0x401F));
    ppt += __int_as_float(__builtin_amdgcn_ds_swizzle(__float_as_int(ppt), 0x401F));
    pm  += __shfl_xor(pm, 32);
    pre += __shfl_xor(pre, 32);
    pim += __shfl_xor(pim, 32);
    ppt += __shfl_xor(ppt, 32);

    float* po = part + (size_t)(blockIdx.x * 4 + wid) * 20;
    if (lane < 16)       po[lane] = pm;
    else if (lane == 16) po[16] = pre;
    else if (lane == 17) po[17] = pim;
    else if (lane == 18) po[18] = ppt;
}

// ---------------- K3: final readout (1 wave per batch) ----------------
__global__ __launch_bounds__(64) void readout_kernel(
    const float* __restrict__ part,  // (4096,20)
    const float* __restrict__ w0, const float* __restrict__ b0,  // (16,32),(32)
    const float* __restrict__ w1, const float* __restrict__ b1,  // (32,32),(32)
    const float* __restrict__ w2, const float* __restrict__ b2,  // (32,1),(1)
    float* __restrict__ out) {
    const int b = blockIdx.x;
    const int t = threadIdx.x;

    __shared__ float sbuf[19];
    __shared__ float xg[18];
    __shared__ float h1r[32];

    if (t < 19) {
        float s0 = 0.0f, s1 = 0.0f, s2 = 0.0f, s3 = 0.0f;
        const float* pb = part + (size_t)b * 32 * 20 + t;
        #pragma unroll
        for (int r = 0; r < 32; r += 4) {
            s0 += pb[(r + 0) * 20];
            s1 += pb[(r + 1) * 20];
            s2 += pb[(r + 2) * 20];
            s3 += pb[(r + 3) * 20];
        }
        sbuf[t] = (s0 + s1) + (s2 + s3);
    }
    // same wave: LDS ops are in-order, no barrier needed
    const float invd = __builtin_amdgcn_rcpf(sbuf[18]);
    if (t < 18) xg[t] = sbuf[t] * invd;

    if (t < 32) {
        float h = b0[t];
        #pragma unroll
        for (int k = 0; k < 16; ++k) h = fmaf(xg[k], w0[k * 32 + t], h);
        h = fmaxf(h, 0.01f * h);
        h1r[t] = h;
    }
    if (t < 32) {
        float h = b1[t];
        #pragma unroll
        for (int k = 0; k < 32; ++k) h = fmaf(h1r[k], w1[k * 32 + t], h);
        h = fmaxf(h, 0.01f * h);
        float p = h * w2[t];
        #pragma unroll
        for (int off = 16; off; off >>= 1) p += __shfl_xor(p, off);
        if (t == 0) {
            out[b * 3 + 0] = 1.0f / (1.0f + expf(-(p + b2[0])));
            out[b * 3 + 1] = xg[16];
            out[b * 3 + 2] = xg[17];
        }
    }
}

extern "C" void kernel_launch(void* const* d_in, const int* in_sizes, int n_in,
                              void* d_out, int out_size, void* d_ws, size_t ws_size,
                              hipStream_t stream) {
    const float* pt    = (const float*)d_in[0];
    const float* ang   = (const float*)d_in[1];
    const float* c0_w0 = (const float*)d_in[2];
    const float* c0_b0 = (const float*)d_in[3];
    const float* c0_w1 = (const float*)d_in[4];
    const float* c0_b1 = (const float*)d_in[5];
    const float* c1_w0 = (const float*)d_in[6];
    const float* c1_b0 = (const float*)d_in[7];
    const float* c1_w1 = (const float*)d_in[8];
    const float* c1_b1 = (const float*)d_in[9];
    const float* r_w0  = (const float*)d_in[10];
    const float* r_b0  = (const float*)d_in[11];
    const float* r_w1  = (const float*)d_in[12];
    const float* r_b1  = (const float*)d_in[13];
    const float* r_w2  = (const float*)d_in[14];
    const float* r_b2  = (const float*)d_in[15];
    float* out = (float*)d_out;
    float* ws = (float*)d_ws;

    float* ang1  = ws;                         // BN*4
    float* u1    = ang1 + (size_t)BN * 4;      // BN*16
    float* v1    = u1 + (size_t)BN * 16;       // BN*16
    float* partb = v1 + (size_t)BN * 16;       // 4096*20

    hipLaunchKernelGGL(conv0_kernel, dim3(BN / 16), dim3(256), 0, stream,
                       ang, c0_w0, c0_b0, c0_w1, c0_b1, c1_w0, c1_b0,
                       ang1, u1, v1);
    hipLaunchKernelGGL(conv1_kernel, dim3(BN / 16), dim3(256), 0, stream,
                       pt, ang1, u1, v1, c1_w0, c1_w1, c1_b1, partb);
    hipLaunchKernelGGL(readout_kernel, dim3(BB), dim3(64), 0, stream,
                       partb, r_w0, r_b0, r_w1, r_b1, r_w2, r_b2, out);
}